// Round 1
// baseline (620.716 us; speedup 1.0000x reference)
//
#include <hip/hip_runtime.h>
#include <hip/hip_bf16.h>
#include <math.h>

#define NT 8192
#define HD 768
#define ID 3072
#define NE 8

typedef __bf16 bf16x8 __attribute__((ext_vector_type(8)));
typedef float f32x4 __attribute__((ext_vector_type(4)));

__device__ __forceinline__ unsigned short f2bf(float f) {
    union { float f; unsigned u; } v; v.f = f;
    unsigned r = v.u + 0x7FFFu + ((v.u >> 16) & 1u);   // RNE
    return (unsigned short)(r >> 16);
}

// CK-style global->LDS direct copy, 16B per lane. LDS dest must be linear
// (wave-uniform base + lane*16); global src is per-lane.
__device__ __forceinline__ void gload16(const void* g, void* l) {
    auto* lds = reinterpret_cast<__attribute__((address_space(3))) unsigned int*>(
        reinterpret_cast<uintptr_t>(l));
    auto* gp = reinterpret_cast<const __attribute__((address_space(1))) unsigned int*>(
        reinterpret_cast<uintptr_t>(g));
    __builtin_amdgcn_global_load_lds(gp, lds, 16, 0, 0);
}

__global__ void k_init(int* counts) {
    if (threadIdx.x < NE) counts[threadIdx.x] = 0;
}

__global__ void k_convertw(const float4* __restrict__ w1, const float4* __restrict__ w2,
                           ushort4* __restrict__ w1b, ushort4* __restrict__ w2b, int n) {
    int i = blockIdx.x * 256 + threadIdx.x;
    if (i >= n) return;
    float4 a = w1[i]; float4 b = w2[i];
    ushort4 ra, rb;
    ra.x = f2bf(a.x); ra.y = f2bf(a.y); ra.z = f2bf(a.z); ra.w = f2bf(a.w);
    rb.x = f2bf(b.x); rb.y = f2bf(b.y); rb.z = f2bf(b.z); rb.w = f2bf(b.w);
    w1b[i] = ra; w2b[i] = rb;
}

// Router: logits fp32 (exact), softmax, top-2 (ties -> lowest index, like lax.top_k),
// append slot=2t+k to expert list, store gate per slot. Also emit x in bf16.
__global__ void k_router(const float* __restrict__ x, const float* __restrict__ rw,
                         unsigned short* __restrict__ xb, float* __restrict__ gates,
                         int* __restrict__ lists, int* __restrict__ counts) {
    __shared__ float rws[NE * HD];     // 24 KB
    const int tid = threadIdx.x;
    for (int i = tid; i < NE * HD; i += 256) rws[i] = rw[i];
    __syncthreads();
    const int wid = tid >> 6, lane = tid & 63;
    const int t = blockIdx.x * 4 + wid;
    const float* xp = x + (size_t)t * HD;
    float acc[NE];
#pragma unroll
    for (int e = 0; e < NE; e++) acc[e] = 0.f;
#pragma unroll
    for (int j = 0; j < HD / 64; j++) {
        float v = xp[lane + 64 * j];
        xb[(size_t)t * HD + lane + 64 * j] = f2bf(v);
#pragma unroll
        for (int e = 0; e < NE; e++) acc[e] += v * rws[e * HD + lane + 64 * j];
    }
#pragma unroll
    for (int e = 0; e < NE; e++)
        for (int off = 32; off; off >>= 1) acc[e] += __shfl_xor(acc[e], off);
    if (lane == 0) {
        float mx = acc[0];
#pragma unroll
        for (int e = 1; e < NE; e++) mx = fmaxf(mx, acc[e]);
        float p[NE], s = 0.f;
#pragma unroll
        for (int e = 0; e < NE; e++) { p[e] = __expf(acc[e] - mx); s += p[e]; }
        float inv = 1.f / s;
        int i1 = 0; float b1 = p[0];
#pragma unroll
        for (int e = 1; e < NE; e++) if (p[e] > b1) { b1 = p[e]; i1 = e; }
        int i2 = (i1 == 0) ? 1 : 0; float b2 = p[i2];
#pragma unroll
        for (int e = 0; e < NE; e++) if (e != i1 && p[e] > b2) { b2 = p[e]; i2 = e; }
        int pos0 = atomicAdd(&counts[i1], 1);
        lists[i1 * NT + pos0] = 2 * t;
        int pos1 = atomicAdd(&counts[i2], 1);
        lists[i2 * NT + pos1] = 2 * t + 1;
        gates[2 * t] = b1 * inv;
        gates[2 * t + 1] = b2 * inv;
    }
}

// GEMM1: h[slot] = gelu(x_gathered @ w1[e]^T). 128x128 tile, BK=32, 4 waves (2x2),
// mfma_f32_16x16x32_bf16, global_load_lds staging, fused exact gelu.
__launch_bounds__(256, 2)
__global__ void k_gemm1(const unsigned short* __restrict__ xb, const unsigned short* __restrict__ w1b,
                        const int* __restrict__ lists, const int* __restrict__ counts,
                        unsigned short* __restrict__ hbuf) {
    const int e = blockIdx.z;
    const int cnt = counts[e];
    const int m0 = blockIdx.x * 128;
    if (m0 >= cnt) return;
    const int n0 = blockIdx.y * 128;
    __shared__ __align__(16) unsigned short As[128 * 32];
    __shared__ __align__(16) unsigned short Bs[128 * 32];
    __shared__ int slot_s[128];
    const int tid = threadIdx.x, lane = tid & 63, wid = tid >> 6;
    if (tid < 128) {
        int r = m0 + tid;
        slot_s[tid] = lists[e * NT + (r < cnt ? r : cnt - 1)];
    }
    __syncthreads();
    const int srow = tid >> 2, scol = (tid & 3) * 8;
    const int tok0 = slot_s[srow] >> 1, tok1 = slot_s[64 + srow] >> 1;
    const unsigned short* gA0 = xb + (size_t)tok0 * HD + scol;
    const unsigned short* gA1 = xb + (size_t)tok1 * HD + scol;
    const unsigned short* gB0 = w1b + ((size_t)(e * ID + n0 + srow)) * HD + scol;
    const unsigned short* gB1 = gB0 + (size_t)64 * HD;
    unsigned short* lA = As + wid * 512;
    unsigned short* lB = Bs + wid * 512;
    const int wr = wid >> 1, wc = wid & 1;
    const bf16x8* pa = (const bf16x8*)(As + (wr * 64 + (lane & 15)) * 32 + (lane >> 4) * 8);
    const bf16x8* pb = (const bf16x8*)(Bs + (wc * 64 + (lane & 15)) * 32 + (lane >> 4) * 8);
    f32x4 acc[4][4];
    f32x4 zero = {0.f, 0.f, 0.f, 0.f};
#pragma unroll
    for (int m = 0; m < 4; m++)
#pragma unroll
        for (int n = 0; n < 4; n++) acc[m][n] = zero;
    for (int kt = 0; kt < HD / 32; ++kt) {
        __syncthreads();
        gload16(gA0, lA); gload16(gA1, lA + 2048);
        gload16(gB0, lB); gload16(gB1, lB + 2048);
        gA0 += 32; gA1 += 32; gB0 += 32; gB1 += 32;
        __syncthreads();
        bf16x8 a[4], b[4];
#pragma unroll
        for (int m = 0; m < 4; m++) a[m] = pa[m * 64];
#pragma unroll
        for (int n = 0; n < 4; n++) b[n] = pb[n * 64];
#pragma unroll
        for (int m = 0; m < 4; m++)
#pragma unroll
            for (int n = 0; n < 4; n++)
                acc[m][n] = __builtin_amdgcn_mfma_f32_16x16x32_bf16(a[m], b[n], acc[m][n], 0, 0, 0);
    }
    const int rj = (lane >> 4) * 4, cn = lane & 15;
#pragma unroll
    for (int m = 0; m < 4; m++) {
#pragma unroll
        for (int j = 0; j < 4; j++) {
            int lr = wr * 64 + m * 16 + rj + j;
            if (m0 + lr < cnt) {
                int slot = slot_s[lr];
                size_t rowoff = (size_t)slot * ID + n0 + wc * 64 + cn;
#pragma unroll
                for (int n = 0; n < 4; n++) {
                    float v = acc[m][n][j];
                    v = 0.5f * v * (1.f + erff(v * 0.70710678118654752f));  // exact gelu
                    hbuf[rowoff + n * 16] = f2bf(v);
                }
            }
        }
    }
}

// GEMM2: pout[slot] = gate[slot] * (h_gathered @ w2[e]^T). Same tile structure, K=3072.
__launch_bounds__(256, 2)
__global__ void k_gemm2(const unsigned short* __restrict__ hbuf, const unsigned short* __restrict__ w2b,
                        const int* __restrict__ lists, const int* __restrict__ counts,
                        const float* __restrict__ gates, float* __restrict__ pout) {
    const int e = blockIdx.z;
    const int cnt = counts[e];
    const int m0 = blockIdx.x * 128;
    if (m0 >= cnt) return;
    const int n0 = blockIdx.y * 128;
    __shared__ __align__(16) unsigned short As[128 * 32];
    __shared__ __align__(16) unsigned short Bs[128 * 32];
    __shared__ int slot_s[128];
    const int tid = threadIdx.x, lane = tid & 63, wid = tid >> 6;
    if (tid < 128) {
        int r = m0 + tid;
        slot_s[tid] = lists[e * NT + (r < cnt ? r : cnt - 1)];
    }
    __syncthreads();
    const int srow = tid >> 2, scol = (tid & 3) * 8;
    const unsigned short* gA0 = hbuf + (size_t)slot_s[srow] * ID + scol;
    const unsigned short* gA1 = hbuf + (size_t)slot_s[64 + srow] * ID + scol;
    const unsigned short* gB0 = w2b + ((size_t)(e * HD + n0 + srow)) * ID + scol;
    const unsigned short* gB1 = gB0 + (size_t)64 * ID;
    unsigned short* lA = As + wid * 512;
    unsigned short* lB = Bs + wid * 512;
    const int wr = wid >> 1, wc = wid & 1;
    const bf16x8* pa = (const bf16x8*)(As + (wr * 64 + (lane & 15)) * 32 + (lane >> 4) * 8);
    const bf16x8* pb = (const bf16x8*)(Bs + (wc * 64 + (lane & 15)) * 32 + (lane >> 4) * 8);
    f32x4 acc[4][4];
    f32x4 zero = {0.f, 0.f, 0.f, 0.f};
#pragma unroll
    for (int m = 0; m < 4; m++)
#pragma unroll
        for (int n = 0; n < 4; n++) acc[m][n] = zero;
    for (int kt = 0; kt < ID / 32; ++kt) {
        __syncthreads();
        gload16(gA0, lA); gload16(gA1, lA + 2048);
        gload16(gB0, lB); gload16(gB1, lB + 2048);
        gA0 += 32; gA1 += 32; gB0 += 32; gB1 += 32;
        __syncthreads();
        bf16x8 a[4], b[4];
#pragma unroll
        for (int m = 0; m < 4; m++) a[m] = pa[m * 64];
#pragma unroll
        for (int n = 0; n < 4; n++) b[n] = pb[n * 64];
#pragma unroll
        for (int m = 0; m < 4; m++)
#pragma unroll
            for (int n = 0; n < 4; n++)
                acc[m][n] = __builtin_amdgcn_mfma_f32_16x16x32_bf16(a[m], b[n], acc[m][n], 0, 0, 0);
    }
    const int rj = (lane >> 4) * 4, cn = lane & 15;
#pragma unroll
    for (int m = 0; m < 4; m++) {
#pragma unroll
        for (int j = 0; j < 4; j++) {
            int lr = wr * 64 + m * 16 + rj + j;
            if (m0 + lr < cnt) {
                int slot = slot_s[lr];
                float g = gates[slot];
                size_t rowoff = (size_t)slot * HD + n0 + wc * 64 + cn;
#pragma unroll
                for (int n = 0; n < 4; n++)
                    pout[rowoff + n * 16] = g * acc[m][n][j];
            }
        }
    }
}

// out[t] = pout[2t] + pout[2t+1] + bias
__global__ void k_combine(const float4* __restrict__ pout, const float* __restrict__ bias,
                          float4* __restrict__ out) {
    int idx = blockIdx.x * 256 + threadIdx.x;   // over NT*HD/4
    int t = idx / (HD / 4);
    int c = idx - t * (HD / 4);
    float4 a = pout[(size_t)t * (2 * HD / 4) + c];
    float4 b = pout[(size_t)t * (2 * HD / 4) + HD / 4 + c];
    float4 bb = ((const float4*)bias)[c];
    float4 r;
    r.x = a.x + b.x + bb.x; r.y = a.y + b.y + bb.y;
    r.z = a.z + b.z + bb.z; r.w = a.w + b.w + bb.w;
    out[idx] = r;
}

extern "C" void kernel_launch(void* const* d_in, const int* in_sizes, int n_in,
                              void* d_out, int out_size, void* d_ws, size_t ws_size,
                              hipStream_t stream) {
    const float* x    = (const float*)d_in[0];
    const float* rw   = (const float*)d_in[1];
    const float* w1   = (const float*)d_in[2];
    const float* w2   = (const float*)d_in[3];
    const float* bias = (const float*)d_in[4];
    float* out = (float*)d_out;

    char* ws = (char*)d_ws;
    size_t off = 0;
    auto alloc = [&](size_t bytes) -> char* {
        char* p = ws + off;
        off += (bytes + 255) & ~(size_t)255;
        return p;
    };
    int*            counts = (int*)alloc(NE * 4);
    int*            lists  = (int*)alloc((size_t)NE * NT * 4);
    float*          gates  = (float*)alloc((size_t)NT * 2 * 4);
    unsigned short* xb     = (unsigned short*)alloc((size_t)NT * HD * 2);
    unsigned short* w1b    = (unsigned short*)alloc((size_t)NE * ID * HD * 2);
    unsigned short* w2b    = (unsigned short*)alloc((size_t)NE * HD * ID * 2);
    unsigned short* hbuf   = (unsigned short*)alloc((size_t)NT * 2 * ID * 2);
    float*          pout   = (float*)alloc((size_t)NT * 2 * HD * 4);

    k_init<<<dim3(1), dim3(64), 0, stream>>>(counts);
    const int n4 = NE * ID * HD / 4;
    k_convertw<<<dim3((n4 + 255) / 256), dim3(256), 0, stream>>>(
        (const float4*)w1, (const float4*)w2, (ushort4*)w1b, (ushort4*)w2b, n4);
    k_router<<<dim3(NT / 4), dim3(256), 0, stream>>>(x, rw, xb, gates, lists, counts);
    k_gemm1<<<dim3(64, ID / 128, NE), dim3(256), 0, stream>>>(xb, w1b, lists, counts, hbuf);
    k_gemm2<<<dim3(64, HD / 128, NE), dim3(256), 0, stream>>>(hbuf, w2b, lists, counts, gates, pout);
    k_combine<<<dim3(NT * HD / 4 / 256), dim3(256), 0, stream>>>((const float4*)pout, bias, (float4*)out);
}